// Round 4
// baseline (409.682 us; speedup 1.0000x reference)
//
#include <hip/hip_runtime.h>

// LSTM B=65536, L=6, H=50, T=3, IN=3, FC 50->1 — fp16 MFMA, R11.
//
// R11 vs R10 (143us, 79% occ): R10 doubled LDS read volume (1 n-tile/wave ->
// no frag sharing) and kept only 2 barrier domains/CU. R11 recombines:
//  - 2 n-tiles/wave (B-frag shared by 2 MFMAs -> LDS reads halved vs R10)
//  - M=32 (2 m-tiles), BLK=512 (8 waves): ring LDS = 5*32*72*2 = 23KB
//    -> FOUR blocks/CU (32 waves, wave-capped) = 4 independent barrier
//    domains; de-correlated post-barrier ds_read convoys + trans bursts.
//  - launch_bounds(512,8) forces <=64 VGPR (pool 512/lane: 8 waves/SIMD).
//    Peak liveness ~64 (W 32 + xa 16 + cc 4 + frags/addr ~12). Spill watch:
//    WRITE_SIZE ballooning = spilled -> fall back to (512,6).
//  - Inner structure = R10's proven monolithic phases (x-part t0 -> h0 stage
//    -> [h-MFMA -> ACT -> x-prefetch] per step), same accumulation order ->
//    bitwise-identical numerics.
// Layout: gates^T = W*X^T, n = 4j+gate; lane holds all 4 gates of unit
// j = 4*ntg+q (lane-local c/h update). One barrier per step + 1 per layer.

namespace {

constexpr int H  = 50;
constexpr int L  = 6;
constexpr int T  = 3;
constexpr int IN = 3;
constexpr int M  = 32;     // samples per block (2 m-tiles)
constexpr int BLK = 512;   // 8 waves, 2 n-tiles each
constexpr int ROWS = 72;   // _Float16 row stride (144 B)
constexpr int NSLOT = 5;   // LDS ring slots

using half8  = __attribute__((ext_vector_type(8))) _Float16;
using half2v = __attribute__((ext_vector_type(2))) _Float16;
using f32x4  = __attribute__((ext_vector_type(4))) float;

__device__ __forceinline__ float rcp_(float x) { return __builtin_amdgcn_rcpf(x); }
__device__ __forceinline__ float ex2(float x)  { return __builtin_amdgcn_exp2f(x); }

// ---------------- prologue: pack fp16 A-fragments, prescaled ----------------
// frag id f = (l*4 + s)*16 + nt ; lane's frag: W[n=16*nt+(lam&15)][k=32*s+(lam>>4)*8+jj]
// Rows prescaled: gate g (n&3==2) by 2/ln2, others by 1/ln2 (bias included).
__global__ void wprep(const float* __restrict__ w_ih0, const float* __restrict__ w_ihL,
                      const float* __restrict__ w_hh,  const float* __restrict__ b_ih,
                      const float* __restrict__ b_hh,  _Float16* __restrict__ wbuf) {
  int t = blockIdx.x * 256 + threadIdx.x;
  if (t >= 384 * 64) return;
  int lam = t & 63, f = t >> 6;
  int nt = f & 15, s = (f >> 4) & 3, l = f >> 6;
  int n = nt * 16 + (lam & 15);
  int j = n >> 2, gate = n & 3, row = gate * 50 + j;  // PyTorch gate order i,f,g,o
  float scale = (gate == 2) ? 2.8853900817779268f : 1.4426950408889634f;
  _Float16 o8[8];
#pragma unroll
  for (int jj = 0; jj < 8; ++jj) {
    int k = s * 32 + (lam >> 4) * 8 + jj;
    float v = 0.f;
    if (j < H) {
      if (s < 2) {                       // x-part, k in [0,64)
        int ksz = (l == 0) ? IN : H;
        if (k < ksz) v = (l == 0) ? w_ih0[row * IN + k]
                                  : w_ihL[((size_t)(l - 1) * 200 + row) * H + k];
      } else {                           // h-part
        int kh = k - 64;
        if (kh < H)        v = w_hh[((size_t)l * 200 + row) * H + kh];
        else if (kh == 63) v = b_ih[l * 200 + row] + b_hh[l * 200 + row];  // bias
      }
    }
    o8[jj] = (_Float16)(v * scale);
  }
  ((half8*)wbuf)[t] = *(half8*)o8;
}

// ---------------- main kernel ----------------
__global__ __launch_bounds__(BLK, 8)   // 8 waves/EU -> cap 64 regs, 4 blocks/CU
void lstm_mfma(const float* __restrict__ x,   const float* __restrict__ h0,
               const float* __restrict__ c0,  const float* __restrict__ fc_w,
               const float* __restrict__ fc_b, const _Float16* __restrict__ wbuf,
               float* __restrict__ out, int B) {
  const int tid = threadIdx.x;
  const int lam = tid & 63;
  const int q   = lam >> 4;
  const int lm  = lam & 15;
  const int bbase = blockIdx.x * M;
  const int ng  = __builtin_amdgcn_readfirstlane(tid >> 6);
  const int ntp = __builtin_amdgcn_readfirstlane((ng + blockIdx.x) & 7);  // pad-wave rotation
  const int ntg0 = 2 * ntp, ntg1 = 2 * ntp + 1;
  const bool live0 = (ntg0 <= 12);          // tiles 13..15 are pure padding (j>=52)
  const bool live1 = (ntg1 <= 12);

  __shared__ __align__(16) _Float16 ys[NSLOT][M][ROWS];   // 23040 B

  // ---- once-only invariant: cols [50,62]=0, col 63=1.0 in ALL slots.
  //      (h-writes touch j<50 only; h0/x staging touch k<50 -> holds forever)
  if (tid < NSLOT * M) {
    _Float16* row = &ys[0][0][0] + (size_t)tid * ROWS;
#pragma unroll
    for (int z = 0; z < 6; ++z)
      *(unsigned int*)(row + 50 + 2 * z) = 0u;            // cols 50..61
    half2v pb; pb[0] = (_Float16)0.f; pb[1] = (_Float16)1.f;
    *(half2v*)(row + 62) = pb;                            // 62=0, 63=1.0
  }
  // ---- x staging into slots 2,3,4 (= sigma(-1,t)): k<3 data, [3,32) zero ----
  if (tid < T * M) {                         // 96 threads, one (t,m) row each
    const int t = tid >> 5, m = tid & 31;
    const float* xs = x + (size_t)(bbase + m) * (IN * T) + t;
    _Float16* row = &ys[2 + t][m][0];
    half2v p0; p0[0] = (_Float16)xs[0]; p0[1] = (_Float16)xs[3];
    half2v p1; p1[0] = (_Float16)xs[6]; p1[1] = (_Float16)0.f;
    *(half2v*)(row)     = p0;
    *(half2v*)(row + 2) = p1;
#pragma unroll
    for (int z = 0; z < 7; ++z)              // k in [4,32) := 0 (layer-0 slab-0 pad)
      *(unsigned long long*)(row + 4 + 4 * z) = 0ull;
  }
  __syncthreads();

  float cc[2][2];
  f32x4 xa[2][2];                            // x-part acc; h-part accumulates in
  half8 W[2][4];                             // [nt][kslab] — 32 regs
  const f32x4 z4 = {0.f, 0.f, 0.f, 0.f};
  int b = 0;                                 // h0 slot for layer l = (4l)%5

  for (int l = 0; l < L; ++l) {
    const int sh0 = b;
    int s1 = b + 1; if (s1 >= NSLOT) s1 -= NSLOT;   // out[0]
    int s2 = b + 2; if (s2 >= NSLOT) s2 -= NSLOT;   // out[1] = x[0]
    int s3 = b + 3; if (s3 >= NSLOT) s3 -= NSLOT;   // out[2] = x[1]
    int s4 = b + 4; if (s4 >= NSLOT) s4 -= NSLOT;   // x[2]

    if (live0) {
      // ---- c0 straight to registers (dead tiles skipped) ----
#pragma unroll
      for (int nt = 0; nt < 2; ++nt) {
        const int ntg = nt ? ntg1 : ntg0;
        const bool lv = nt ? live1 : live0;
        const int j = 4 * ntg + q;
#pragma unroll
        for (int mt = 0; mt < 2; ++mt)
          cc[nt][mt] = (lv && j < H)
              ? c0[((size_t)l * B + bbase + mt * 16 + lm) * H + j] : 0.f;
      }
      // ---- W fragments for this layer (live tiles only, coalesced) ----
#pragma unroll
      for (int nt = 0; nt < 2; ++nt) {
        const int ntg = nt ? ntg1 : ntg0;
        const bool lv = nt ? live1 : live0;
        if (lv)
#pragma unroll
          for (int s = 0; s < 4; ++s)
            W[nt][s] = ((const half8*)wbuf)[((l * 4 + s) * 16 + ntg) * 64 + lam];
      }
      // ---- x-part of t=0 from x[0]=s2 (stable since prev barrier) ----
#pragma unroll
      for (int s = 0; s < 2; ++s) {
        if (s == 1 && l == 0) continue;       // layer-0 slab 1 is all-zero W: skip
        half8 Xf[2];
#pragma unroll
        for (int mt = 0; mt < 2; ++mt)
          Xf[mt] = *(const half8*)(&ys[s2][mt * 16 + lm][s * 32 + q * 8]);
#pragma unroll
        for (int mt = 0; mt < 2; ++mt)
          xa[0][mt] = __builtin_amdgcn_mfma_f32_16x16x32_f16(
              W[0][s], Xf[mt], s == 0 ? z4 : xa[0][mt], 0, 0, 0);
        if (live1)
#pragma unroll
          for (int mt = 0; mt < 2; ++mt)
            xa[1][mt] = __builtin_amdgcn_mfma_f32_16x16x32_f16(
                W[1][s], Xf[mt], s == 0 ? z4 : xa[1][mt], 0, 0, 0);
      }
    }
    // ---- stage h0 into slot sh0, pair-packed, all 512 threads ----
    {
      const int mg = tid >> 4, kpl = tid & 15;           // 16 threads per row, 32 rows
      const float* hp = h0 + ((size_t)l * B + bbase + mg) * H + 2 * kpl;
      _Float16* dp = &ys[sh0][mg][2 * kpl];
      float2 v = *(const float2*)(hp);
      half2v pv; pv[0] = (_Float16)v.x; pv[1] = (_Float16)v.y;
      *(half2v*)dp = pv;
      if (kpl < 9) {                                     // pairs 16..24 (k 32..49)
        float2 v2 = *(const float2*)(hp + 32);
        half2v p2; p2[0] = (_Float16)v2.x; p2[1] = (_Float16)v2.y;
        *(half2v*)(dp + 32) = p2;
      }
    }
    __syncthreads();

#pragma unroll
    for (int t = 0; t < T; ++t) {
      const int shs = (t == 0) ? sh0 : ((t == 1) ? s1 : s2);  // h-source slot
      const int sot = (t == 0) ? s1  : ((t == 1) ? s2 : s3);  // h-dest slot
      const int sxt = (t == 0) ? s3  : s4;                    // x-prefetch slot
      if (live0) {                                        // all-dead wave skips compute
        // ---- h-part: slabs 2,3 accumulate onto prefetched x-part ----
#pragma unroll
        for (int s = 0; s < 2; ++s) {
          half8 Hf[2];
#pragma unroll
          for (int mt = 0; mt < 2; ++mt)
            Hf[mt] = *(const half8*)(&ys[shs][mt * 16 + lm][s * 32 + q * 8]);
#pragma unroll
          for (int mt = 0; mt < 2; ++mt)
            xa[0][mt] = __builtin_amdgcn_mfma_f32_16x16x32_f16(
                W[0][2 + s], Hf[mt], xa[0][mt], 0, 0, 0);
          if (live1)
#pragma unroll
            for (int mt = 0; mt < 2; ++mt)
              xa[1][mt] = __builtin_amdgcn_mfma_f32_16x16x32_f16(
                  W[1][2 + s], Hf[mt], xa[1][mt], 0, 0, 0);
        }
        // ---- activations: prescaled gates -> sigm = rcp(1+exp2(-g)) ----
#pragma unroll
        for (int nt = 0; nt < 2; ++nt) {
          if (nt && !live1) continue;
          const int ntg = nt ? ntg1 : ntg0;
          const int j = 4 * ntg + q;
#pragma unroll
          for (int mt = 0; mt < 2; ++mt) {
            const float ig = rcp_(1.f + ex2(-xa[nt][mt][0]));
            const float fg = rcp_(1.f + ex2(-xa[nt][mt][1]));
            const float gg = 2.f * rcp_(1.f + ex2(-xa[nt][mt][2])) - 1.f;
            const float og = rcp_(1.f + ex2(-xa[nt][mt][3]));
            const float cv = fg * cc[nt][mt] + ig * gg;
            cc[nt][mt] = cv;
            const float tc = 2.f * rcp_(1.f + ex2(-2.8853900817779268f * cv)) - 1.f;
            if (j < H)                        // pad cols (and k63=1.0) stay intact
              ys[sot][mt * 16 + lm][j] = (_Float16)(og * tc);
          }
        }
        // ---- x-part prefetch for t+1 (slot stable; fills barrier window) ----
        if (t < T - 1) {
#pragma unroll
          for (int s = 0; s < 2; ++s) {
            if (s == 1 && l == 0) continue;
            half8 Xf[2];
#pragma unroll
            for (int mt = 0; mt < 2; ++mt)
              Xf[mt] = *(const half8*)(&ys[sxt][mt * 16 + lm][s * 32 + q * 8]);
#pragma unroll
            for (int mt = 0; mt < 2; ++mt)
              xa[0][mt] = __builtin_amdgcn_mfma_f32_16x16x32_f16(
                  W[0][s], Xf[mt], s == 0 ? z4 : xa[0][mt], 0, 0, 0);
            if (live1)
#pragma unroll
              for (int mt = 0; mt < 2; ++mt)
                xa[1][mt] = __builtin_amdgcn_mfma_f32_16x16x32_f16(
                    W[1][s], Xf[mt], s == 0 ? z4 : xa[1][mt], 0, 0, 0);
          }
        }
      }
      __syncthreads();   // h_t (and, at t=T-1, layer output) visible
    }
    b = (b == 0) ? (NSLOT - 1) : b - 1;      // (4(l+1))%5 = b-1 mod 5
  }

  // ---- fc tail: out[b] = fc_w · h_last + fc_b ----
  // final h slot = sigma(L-1, T-1) = (4*5+3)%5 = 3
  if (tid < 8 * M) {
    int m = tid >> 3, strip = tid & 7;
    float part = 0.f;
#pragma unroll
    for (int jj = 0; jj < 7; ++jj) {
      int jf = strip + 8 * jj;
      if (jf < H) part += fc_w[jf] * (float)ys[3][m][jf];
    }
    part += __shfl_xor(part, 4);
    part += __shfl_xor(part, 2);
    part += __shfl_xor(part, 1);
    if (strip == 0) out[bbase + m] = part + fc_b[0];
  }
}

}  // namespace

extern "C" void kernel_launch(void* const* d_in, const int* in_sizes, int n_in,
                              void* d_out, int out_size, void* d_ws, size_t ws_size,
                              hipStream_t stream) {
  const float* x     = (const float*)d_in[0];
  const float* h0    = (const float*)d_in[1];
  const float* c0    = (const float*)d_in[2];
  const float* w_ih0 = (const float*)d_in[3];
  const float* w_ih  = (const float*)d_in[4];
  const float* w_hh  = (const float*)d_in[5];
  const float* b_ih  = (const float*)d_in[6];
  const float* b_hh  = (const float*)d_in[7];
  const float* fc_w  = (const float*)d_in[8];
  const float* fc_b  = (const float*)d_in[9];
  float* out         = (float*)d_out;

  const int B = in_sizes[0] / (IN * T);  // 65536
  _Float16* wbuf = (_Float16*)d_ws;      // 384 frags * 64 lanes * 16 B = 393 KB

  wprep<<<(384 * 64 + 255) / 256, 256, 0, stream>>>(w_ih0, w_ih, w_hh, b_ih, b_hh, wbuf);
  lstm_mfma<<<B / M, BLK, 0, stream>>>(x, h0, c0, fc_w, fc_b, wbuf, out, B);
}

// Round 5
// 279.190 us; speedup vs baseline: 1.4674x; 1.4674x over previous
//
#include <hip/hip_runtime.h>

// LSTM B=65536, L=6, H=50, T=3, IN=3, FC 50->1 — fp16 MFMA, R12.
//
// R12 vs R11 (spilled: combined arch+acc VGPR budget is what launch_bounds
// caps; 64 was too small for 2-tile M=32 state) and R10 (143us, LDS-read
// duplication ~48% busy + addr VALU ~35% of VALUBusy):
//  - M=16 (ONE m-tile), BLK=512, 8 waves x 2 n-tiles: keeps B-frag sharing
//    (each ds_read feeds 2 MFMAs) while state fits the proven 64-combined
//    regime: W 32 + xa 8(acc) + cc 2 + misc ~ 58.
//  - Ring-5 LDS = 5*16*72*2 = 11.5KB -> 4 blocks/CU (32 waves = occupancy
//    cap) = 4 independent barrier domains; post-barrier convoys de-correlate.
//  - Layer loop force-unrolled -> ring slots compile-time -> every ds_read/
//    ds_write is one per-lane base VGPR + immediate offset (kills ~50 addr
//    VALU per wave-step seen in R10).
//  - LDS reads per M=64-work: 364 -> ~112 b128 (7 live waves x 4 reads x 4
//    blocks for same work).
//  - Same accumulation order as R10/R11 -> bitwise-identical numerics.
// Layout: gates^T = W*X^T, n = 4j+gate; lane holds all 4 gates of unit
// j = 4*ntg+q, sample = lm (lane-local c/h update). 1 barrier/step + 1/layer.

namespace {

constexpr int H  = 50;
constexpr int L  = 6;
constexpr int T  = 3;
constexpr int IN = 3;
constexpr int M  = 16;     // samples per block (ONE m-tile)
constexpr int BLK = 512;   // 8 waves, 2 n-tiles each
constexpr int ROWS = 72;   // _Float16 row stride (144 B)
constexpr int NSLOT = 5;   // LDS ring slots

using half8  = __attribute__((ext_vector_type(8))) _Float16;
using half2v = __attribute__((ext_vector_type(2))) _Float16;
using f32x4  = __attribute__((ext_vector_type(4))) float;

__device__ __forceinline__ float rcp_(float x) { return __builtin_amdgcn_rcpf(x); }
__device__ __forceinline__ float ex2(float x)  { return __builtin_amdgcn_exp2f(x); }

// ---------------- prologue: pack fp16 A-fragments, prescaled ----------------
// frag id f = (l*4 + s)*16 + nt ; lane's frag: W[n=16*nt+(lam&15)][k=32*s+(lam>>4)*8+jj]
// Rows prescaled: gate g (n&3==2) by 2/ln2, others by 1/ln2 (bias included).
__global__ void wprep(const float* __restrict__ w_ih0, const float* __restrict__ w_ihL,
                      const float* __restrict__ w_hh,  const float* __restrict__ b_ih,
                      const float* __restrict__ b_hh,  _Float16* __restrict__ wbuf) {
  int t = blockIdx.x * 256 + threadIdx.x;
  if (t >= 384 * 64) return;
  int lam = t & 63, f = t >> 6;
  int nt = f & 15, s = (f >> 4) & 3, l = f >> 6;
  int n = nt * 16 + (lam & 15);
  int j = n >> 2, gate = n & 3, row = gate * 50 + j;  // PyTorch gate order i,f,g,o
  float scale = (gate == 2) ? 2.8853900817779268f : 1.4426950408889634f;
  _Float16 o8[8];
#pragma unroll
  for (int jj = 0; jj < 8; ++jj) {
    int k = s * 32 + (lam >> 4) * 8 + jj;
    float v = 0.f;
    if (j < H) {
      if (s < 2) {                       // x-part, k in [0,64)
        int ksz = (l == 0) ? IN : H;
        if (k < ksz) v = (l == 0) ? w_ih0[row * IN + k]
                                  : w_ihL[((size_t)(l - 1) * 200 + row) * H + k];
      } else {                           // h-part
        int kh = k - 64;
        if (kh < H)        v = w_hh[((size_t)l * 200 + row) * H + kh];
        else if (kh == 63) v = b_ih[l * 200 + row] + b_hh[l * 200 + row];  // bias
      }
    }
    o8[jj] = (_Float16)(v * scale);
  }
  ((half8*)wbuf)[t] = *(half8*)o8;
}

// ---------------- main kernel ----------------
__global__ __launch_bounds__(BLK, 8)   // 8 waves/EU -> 64 combined regs, 4 blocks/CU
void lstm_mfma(const float* __restrict__ x,   const float* __restrict__ h0,
               const float* __restrict__ c0,  const float* __restrict__ fc_w,
               const float* __restrict__ fc_b, const _Float16* __restrict__ wbuf,
               float* __restrict__ out, int B) {
  const int tid = threadIdx.x;
  const int lam = tid & 63;
  const int q   = lam >> 4;
  const int lm  = lam & 15;
  const int bbase = blockIdx.x * M;
  const int ng  = __builtin_amdgcn_readfirstlane(tid >> 6);
  const int ntp = __builtin_amdgcn_readfirstlane((ng + blockIdx.x) & 7);  // pad-wave rotation
  const int ntg0 = 2 * ntp, ntg1 = 2 * ntp + 1;
  const bool live0 = (ntg0 <= 12);          // tiles 13..15 are pure padding (j>=52)
  const bool live1 = (ntg1 <= 12);
  const int j0 = 4 * ntg0 + q, j1 = 4 * ntg1 + q;  // units this lane owns

  __shared__ __align__(16) _Float16 ys[NSLOT][M][ROWS];   // 11520 B

  // ---- once-only invariant: cols [50,62]=0, col 63=1.0 in ALL slots.
  //      (h-writes touch j<50 only; h0/x staging touch k<50 -> holds forever)
  if (tid < NSLOT * M) {
    _Float16* row = &ys[0][0][0] + (size_t)tid * ROWS;
#pragma unroll
    for (int z = 0; z < 6; ++z)
      *(unsigned int*)(row + 50 + 2 * z) = 0u;            // cols 50..61
    half2v pb; pb[0] = (_Float16)0.f; pb[1] = (_Float16)1.f;
    *(half2v*)(row + 62) = pb;                            // 62=0, 63=1.0
  }
  // ---- x staging into slots 2,3,4 (= sigma(-1,t)): k<3 data, [3,32) zero ----
  if (tid < T * M) {                         // 48 threads, one (t,m) row each
    const int t = tid >> 4, m = tid & 15;
    const float* xs = x + (size_t)(bbase + m) * (IN * T) + t;
    _Float16* row = &ys[2 + t][m][0];
    half2v p0; p0[0] = (_Float16)xs[0]; p0[1] = (_Float16)xs[3];
    half2v p1; p1[0] = (_Float16)xs[6]; p1[1] = (_Float16)0.f;
    *(half2v*)(row)     = p0;
    *(half2v*)(row + 2) = p1;
#pragma unroll
    for (int z = 0; z < 7; ++z)              // k in [4,32) := 0 (layer-0 slab-0 pad)
      *(unsigned long long*)(row + 4 + 4 * z) = 0ull;
  }
  __syncthreads();

  float cc[2];
  f32x4 xa[2];                               // x-part acc; h-part accumulates in
  half8 W[2][4];                             // [nt][kslab] — 32 regs
  const f32x4 z4 = {0.f, 0.f, 0.f, 0.f};

  // per-lane LDS read base: row lm, k-offset q*8 (bytes); slot/slab are imm
  const _Float16* rbase = &ys[0][lm][q * 8];

#pragma unroll
  for (int l = 0; l < L; ++l) {
    // ring slots, compile-time under full unroll
    const int sh0 = (4 * l) % 5;             // h0 / h-source t=0
    const int s1 = (sh0 + 1) % 5;            // out[0]
    const int s2 = (sh0 + 2) % 5;            // out[1] = x[0]
    const int s3 = (sh0 + 3) % 5;            // out[2] = x[1]
    const int s4 = (sh0 + 4) % 5;            // x[2]

    if (live0) {
      // ---- c0 straight to registers (dead tile -> 0) ----
      cc[0] = (j0 < H) ? c0[((size_t)l * B + bbase + lm) * H + j0] : 0.f;
      cc[1] = (live1 && j1 < H) ? c0[((size_t)l * B + bbase + lm) * H + j1] : 0.f;
      // ---- W fragments for this layer (live tiles only, coalesced) ----
#pragma unroll
      for (int s = 0; s < 4; ++s)
        W[0][s] = ((const half8*)wbuf)[((l * 4 + s) * 16 + ntg0) * 64 + lam];
      if (live1)
#pragma unroll
        for (int s = 0; s < 4; ++s)
          W[1][s] = ((const half8*)wbuf)[((l * 4 + s) * 16 + ntg1) * 64 + lam];
      // ---- x-part of t=0 from x[0]=s2 (stable since prev barrier) ----
      {
        half8 Xf = *(const half8*)(rbase + s2 * (M * ROWS));
        xa[0] = __builtin_amdgcn_mfma_f32_16x16x32_f16(W[0][0], Xf, z4, 0, 0, 0);
        if (live1)
          xa[1] = __builtin_amdgcn_mfma_f32_16x16x32_f16(W[1][0], Xf, z4, 0, 0, 0);
        if (l > 0) {                         // layer-0 slab 1 is all-zero W: skip
          half8 Xg = *(const half8*)(rbase + s2 * (M * ROWS) + 32);
          xa[0] = __builtin_amdgcn_mfma_f32_16x16x32_f16(W[0][1], Xg, xa[0], 0, 0, 0);
          if (live1)
            xa[1] = __builtin_amdgcn_mfma_f32_16x16x32_f16(W[1][1], Xg, xa[1], 0, 0, 0);
        }
      }
    }
    // ---- stage h0 into slot sh0, pair-packed (16 rows x 25 pairs) ----
    {
      const int mg = tid >> 5, kpl = tid & 31;           // 32 threads per row
      if (kpl < 25) {
        float2 v = *(const float2*)(h0 + ((size_t)l * B + bbase + mg) * H + 2 * kpl);
        half2v pv; pv[0] = (_Float16)v.x; pv[1] = (_Float16)v.y;
        *(half2v*)(&ys[sh0][mg][2 * kpl]) = pv;
      }
    }
    __syncthreads();

#pragma unroll
    for (int t = 0; t < T; ++t) {
      const int shs = (t == 0) ? sh0 : ((t == 1) ? s1 : s2);  // h-source slot
      const int sot = (t == 0) ? s1  : ((t == 1) ? s2 : s3);  // h-dest slot
      const int sxt = (t == 0) ? s3  : s4;                    // x-prefetch slot
      if (live0) {                                        // all-dead wave skips compute
        // ---- h-part: slabs 2,3 accumulate onto prefetched x-part ----
#pragma unroll
        for (int s = 0; s < 2; ++s) {
          half8 Hf = *(const half8*)(rbase + shs * (M * ROWS) + s * 32);
          xa[0] = __builtin_amdgcn_mfma_f32_16x16x32_f16(W[0][2 + s], Hf, xa[0], 0, 0, 0);
          if (live1)
            xa[1] = __builtin_amdgcn_mfma_f32_16x16x32_f16(W[1][2 + s], Hf, xa[1], 0, 0, 0);
        }
        // ---- activations: prescaled gates -> sigm = rcp(1+exp2(-g)) ----
        {
          const float ig = rcp_(1.f + ex2(-xa[0][0]));
          const float fg = rcp_(1.f + ex2(-xa[0][1]));
          const float gg = 2.f * rcp_(1.f + ex2(-xa[0][2])) - 1.f;
          const float og = rcp_(1.f + ex2(-xa[0][3]));
          const float cv = fg * cc[0] + ig * gg;
          cc[0] = cv;
          const float tc = 2.f * rcp_(1.f + ex2(-2.8853900817779268f * cv)) - 1.f;
          if (j0 < H)                         // pad cols (and k63=1.0) stay intact
            ys[sot][lm][j0] = (_Float16)(og * tc);
        }
        if (live1) {
          const float ig = rcp_(1.f + ex2(-xa[1][0]));
          const float fg = rcp_(1.f + ex2(-xa[1][1]));
          const float gg = 2.f * rcp_(1.f + ex2(-xa[1][2])) - 1.f;
          const float og = rcp_(1.f + ex2(-xa[1][3]));
          const float cv = fg * cc[1] + ig * gg;
          cc[1] = cv;
          const float tc = 2.f * rcp_(1.f + ex2(-2.8853900817779268f * cv)) - 1.f;
          if (j1 < H)
            ys[sot][lm][j1] = (_Float16)(og * tc);
        }
        // ---- x-part prefetch for t+1 (slot stable; fills barrier window) ----
        if (t < T - 1) {
          half8 Xf = *(const half8*)(rbase + sxt * (M * ROWS));
          xa[0] = __builtin_amdgcn_mfma_f32_16x16x32_f16(W[0][0], Xf, z4, 0, 0, 0);
          if (live1)
            xa[1] = __builtin_amdgcn_mfma_f32_16x16x32_f16(W[1][0], Xf, z4, 0, 0, 0);
          if (l > 0) {
            half8 Xg = *(const half8*)(rbase + sxt * (M * ROWS) + 32);
            xa[0] = __builtin_amdgcn_mfma_f32_16x16x32_f16(W[0][1], Xg, xa[0], 0, 0, 0);
            if (live1)
              xa[1] = __builtin_amdgcn_mfma_f32_16x16x32_f16(W[1][1], Xg, xa[1], 0, 0, 0);
          }
        }
      }
      __syncthreads();   // h_t (and, at t=T-1, layer output) visible
    }
  }

  // ---- fc tail: out[b] = fc_w · h_last + fc_b ----
  // final h slot = sigma(L-1, T-1) = (4*5+3)%5 = 3
  if (tid < 8 * M) {
    int m = tid >> 3, strip = tid & 7;
    float part = 0.f;
#pragma unroll
    for (int jj = 0; jj < 7; ++jj) {
      int jf = strip + 8 * jj;
      if (jf < H) part += fc_w[jf] * (float)ys[3][m][jf];
    }
    part += __shfl_xor(part, 4);
    part += __shfl_xor(part, 2);
    part += __shfl_xor(part, 1);
    if (strip == 0) out[bbase + m] = part + fc_b[0];
  }
}

}  // namespace

extern "C" void kernel_launch(void* const* d_in, const int* in_sizes, int n_in,
                              void* d_out, int out_size, void* d_ws, size_t ws_size,
                              hipStream_t stream) {
  const float* x     = (const float*)d_in[0];
  const float* h0    = (const float*)d_in[1];
  const float* c0    = (const float*)d_in[2];
  const float* w_ih0 = (const float*)d_in[3];
  const float* w_ih  = (const float*)d_in[4];
  const float* w_hh  = (const float*)d_in[5];
  const float* b_ih  = (const float*)d_in[6];
  const float* b_hh  = (const float*)d_in[7];
  const float* fc_w  = (const float*)d_in[8];
  const float* fc_b  = (const float*)d_in[9];
  float* out         = (float*)d_out;

  const int B = in_sizes[0] / (IN * T);  // 65536
  _Float16* wbuf = (_Float16*)d_ws;      // 384 frags * 64 lanes * 16 B = 393 KB

  wprep<<<(384 * 64 + 255) / 256, 256, 0, stream>>>(w_ih0, w_ih, w_hh, b_ih, b_hh, wbuf);
  lstm_mfma<<<B / M, BLK, 0, stream>>>(x, h0, c0, fc_w, fc_b, wbuf, out, B);
}